// Round 4
// baseline (1111.351 us; speedup 1.0000x reference)
//
#include <hip/hip_runtime.h>
#include <math.h>

// Problem constants (B=4, T=512, H=2048, V=32000)
#define BATCH 4
#define TSEQ 512
#define MTOK 2048          // B*T
#define HDIM 2048
#define VOCAB 32000
#define NCHUNK 500         // VOCAB / 64
#define IGNORE_INDEX (-100)
#define BETA 0.1f

// convert geometry: 8192 float4s per block (256 thr x 32), wave-contiguous
#define CVT_PER_BLOCK 8192
#define WCVT_BLK (VOCAB * HDIM / 4 / CVT_PER_BLOCK)   // 2000 blocks per W
#define XCVT_BLK (MTOK * HDIM / 4 / CVT_PER_BLOCK)    // 128 blocks per x

typedef __attribute__((ext_vector_type(4))) float floatx4;
typedef __attribute__((ext_vector_type(8))) short short8;
typedef __attribute__((ext_vector_type(4))) unsigned short ushortx4;

// ---------------------------------------------------------------- utilities
__device__ __forceinline__ unsigned short f2bf(float f) {
    unsigned int u = __float_as_uint(f);
    u += 0x7fffu + ((u >> 16) & 1u);   // RNE
    return (unsigned short)(u >> 16);
}

__device__ __forceinline__ void async_copy16(const unsigned short* g, unsigned short* l) {
    __builtin_amdgcn_global_load_lds(
        (const __attribute__((address_space(1))) void*)g,
        (__attribute__((address_space(3))) void*)l, 16, 0, 0);
}

// One block converts CVT_PER_BLOCK float4s. Every load instruction is 16 B/lane
// contiguous across the wave (1 KB/wave); stores are 8 B/lane contiguous.
// (R3's version had lanes at 32 B stride per load + 68k micro-blocks.)
__device__ __forceinline__ void cvt_run(const float* __restrict__ src,
                                        unsigned short* __restrict__ dst,
                                        int relblk) {
    size_t base = (size_t)relblk * CVT_PER_BLOCK + threadIdx.x;
    const floatx4* s4 = (const floatx4*)src;
    ushortx4* d4 = (ushortx4*)dst;
#pragma unroll
    for (int k = 0; k < 32; ++k) {
        floatx4 a = s4[base + k * 256];
        ushortx4 o;
        o[0] = f2bf(a[0]); o[1] = f2bf(a[1]);
        o[2] = f2bf(a[2]); o[3] = f2bf(a[3]);
        d4[base + k * 256] = o;
    }
}

// --------------------------------------------- fp32 -> bf16, all 4 tensors
// grid = 2*WCVT_BLK + 2*XCVT_BLK = 4256 blocks
__global__ __launch_bounds__(256) void cvt_all_kernel(
        const float* __restrict__ s0, const float* __restrict__ s1,
        const float* __restrict__ s2, const float* __restrict__ s3,
        unsigned short* __restrict__ d0, unsigned short* __restrict__ d1,
        unsigned short* __restrict__ d2, unsigned short* __restrict__ d3) {
    int b = blockIdx.x;
    if (b < WCVT_BLK)                   cvt_run(s0, d0, b);
    else if (b < 2 * WCVT_BLK)          cvt_run(s1, d1, b - WCVT_BLK);
    else if (b < 2 * WCVT_BLK + XCVT_BLK) cvt_run(s2, d2, b - 2 * WCVT_BLK);
    else                                cvt_run(s3, d3, b - 2 * WCVT_BLK - XCVT_BLK);
}

// ------------------------------------------------ fp32 -> bf16, one tensor
__global__ __launch_bounds__(256) void cvt_one_kernel(
        const float* __restrict__ src, unsigned short* __restrict__ dst) {
    cvt_run(src, dst, blockIdx.x);
}

// ------------------------------------------------------- GEMM + fused LSE
// C = Xb (M x H) * Wb^T (V x H)  -> per-token (max, sumexp) per 64-vocab chunk
// grid = (M/128, V/128, nmodels), block = 256 (4 waves, each 64x64)
// LDS layout is XOR-swizzled: global 16B-chunk g of row r sits at chunk
// position g^(r&7); staging permutes the SOURCE address (global_load_lds dest
// must remain wave-uniform base + lane*16); reads apply the matching XOR.
#define BK 64
__global__ __launch_bounds__(256, 2) void gemm_lse_kernel(
        const unsigned short* __restrict__ Xb0,
        const unsigned short* __restrict__ Xb1,
        const unsigned short* __restrict__ Wb0,
        const unsigned short* __restrict__ Wb1,
        const int* __restrict__ y,               // M labels
        float* __restrict__ pmax,                // [slot][M][NCHUNK]
        float* __restrict__ psum,                // [slot][M][NCHUNK]
        float* __restrict__ tlog,                // [slot][M]
        int slot_base)
{
    __shared__ __align__(16) unsigned short sA[128 * BK];
    __shared__ __align__(16) unsigned short sB[128 * BK];

    const int slot = slot_base + blockIdx.z;
    const unsigned short* __restrict__ Xb = slot ? Xb1 : Xb0;
    const unsigned short* __restrict__ Wb = slot ? Wb1 : Wb0;

    const int tid  = threadIdx.x;
    const int m0   = blockIdx.x * 128;
    const int v0   = blockIdx.y * 128;
    const int w    = tid >> 6;
    const int lane = tid & 63;
    const int wm   = w & 1;         // token half
    const int wn   = w >> 1;        // vocab half
    const int c    = lane & 15;
    const int q    = lane >> 4;

    floatx4 acc[4][4] = {};

    const int e0 = tid * 8;

    for (int kt = 0; kt < HDIM / BK; ++kt) {
        const int k0 = kt * BK;
#pragma unroll
        for (int it = 0; it < 4; ++it) {
            int e   = it * 2048 + e0;
            int row = e >> 6;                    // 0..127
            int p   = (e >> 3) & 7;              // LDS chunk position
            int col = (p ^ (row & 7)) * 8;       // swizzled global chunk
            async_copy16(Xb + (size_t)(m0 + row) * HDIM + (k0 + col), &sA[e]);
            async_copy16(Wb + (size_t)(v0 + row) * HDIM + (k0 + col), &sB[e]);
        }
        __syncthreads();
#pragma unroll
        for (int kk = 0; kk < BK; kk += 32) {
            short8 af[4], bf[4];
            const int gq = (kk >> 3) + q;        // wanted global chunk 0..7
            const int pq = gq ^ (c & 7);         // its swizzled LDS position
#pragma unroll
            for (int i = 0; i < 4; ++i)
                af[i] = *(const short8*)&sA[(wm * 64 + i * 16 + c) * BK + pq * 8];
#pragma unroll
            for (int j = 0; j < 4; ++j)
                bf[j] = *(const short8*)&sB[(wn * 64 + j * 16 + c) * BK + pq * 8];
#pragma unroll
            for (int i = 0; i < 4; ++i)
#pragma unroll
                for (int j = 0; j < 4; ++j)
                    acc[i][j] = __builtin_amdgcn_mfma_f32_16x16x32_bf16(
                        af[i], bf[j], acc[i][j], 0, 0, 0);
        }
        __syncthreads();
    }

    // Epilogue: C/D layout col = lane&15 (vocab), row = q*4+r (token)
    const int chunk = blockIdx.y * 2 + wn;   // 64-vocab chunk id
#pragma unroll
    for (int i = 0; i < 4; ++i) {
        float mx[4], sm[4];
#pragma unroll
        for (int r = 0; r < 4; ++r) {
            float m4 = acc[i][0][r];
            m4 = fmaxf(m4, acc[i][1][r]);
            m4 = fmaxf(m4, acc[i][2][r]);
            m4 = fmaxf(m4, acc[i][3][r]);
            mx[r] = m4;
        }
#pragma unroll
        for (int d = 1; d < 16; d <<= 1)
#pragma unroll
            for (int r = 0; r < 4; ++r)
                mx[r] = fmaxf(mx[r], __shfl_xor(mx[r], d, 64));
#pragma unroll
        for (int r = 0; r < 4; ++r) {
            float s = 0.f;
#pragma unroll
            for (int j = 0; j < 4; ++j) s += expf(acc[i][j][r] - mx[r]);
            sm[r] = s;
        }
#pragma unroll
        for (int d = 1; d < 16; d <<= 1)
#pragma unroll
            for (int r = 0; r < 4; ++r)
                sm[r] += __shfl_xor(sm[r], d, 64);

        const int tokenBase = m0 + wm * 64 + i * 16 + q * 4;
        if (c == 0) {
#pragma unroll
            for (int r = 0; r < 4; ++r) {
                pmax[(size_t)(slot * MTOK + tokenBase + r) * NCHUNK + chunk] = mx[r];
                psum[(size_t)(slot * MTOK + tokenBase + r) * NCHUNK + chunk] = sm[r];
            }
        }
        // target-logit capture — LITERAL j index only (runtime index into acc
        // demotes the accumulator to scratch: R1's 12 GB WRITE_SIZE bug)
#pragma unroll
        for (int r = 0; r < 4; ++r) {
            int lab = y[tokenBase + r];
            int rel = lab - (v0 + wn * 64);
            if (rel >= 0 && rel < 64 && (rel & 15) == c) {
#pragma unroll
                for (int j = 0; j < 4; ++j)
                    if ((rel >> 4) == j)
                        tlog[(size_t)slot * MTOK + tokenBase + r] = acc[i][j][r];
            }
        }
    }
}

// --------------------------------------------- per-token logp (wave/token)
// grid = (MTOK/4, nmodels), block = 256 (4 waves, one token each)
__global__ __launch_bounds__(256) void finalize_kernel(
        const int* __restrict__ y,
        const float* __restrict__ pmax,
        const float* __restrict__ psum,
        const float* __restrict__ tlog,
        float* __restrict__ tokll, int slot_base) {
    const int wv    = threadIdx.x >> 6;
    const int lane  = threadIdx.x & 63;
    const int token = blockIdx.x * 4 + wv;
    const int slot  = slot_base + blockIdx.y;

    const float* pm = &pmax[(size_t)(slot * MTOK + token) * NCHUNK];
    const float* ps = &psum[(size_t)(slot * MTOK + token) * NCHUNK];
    float m = -3.4e38f, s = 0.f;
    for (int c2 = lane; c2 < NCHUNK; c2 += 64) {
        float cm = pm[c2];
        float cs = ps[c2];
        if (cm > m) { s = s * expf(m - cm) + cs; m = cm; }
        else        { s += cs * expf(cm - m); }
    }
#pragma unroll
    for (int d = 1; d < 64; d <<= 1) {
        float om = __shfl_xor(m, d, 64);
        float os = __shfl_xor(s, d, 64);
        if (om > m) { s = s * expf(m - om) + os; m = om; }
        else        { s += os * expf(om - m); }
    }
    if (lane == 0) {
        int lab = y[token];
        float lse = m + logf(s);
        tokll[(size_t)slot * MTOK + token] =
            (lab == IGNORE_INDEX) ? 0.f : (tlog[(size_t)slot * MTOK + token] - lse);
    }
}

// ---------------------------------- fused seq-average + KTO loss, 1 block
__global__ __launch_bounds__(256) void tail_kernel(
        const int* __restrict__ y,
        const float* __restrict__ tokll,
        const int* __restrict__ pref,
        float* __restrict__ out) {
    __shared__ float rs[256];
    __shared__ float rc[256];
    __shared__ float seqavg[8];
    const int tid = threadIdx.x;
    for (int sb = 0; sb < 8; ++sb) {
        const int slot = sb >> 2;
        const int b    = sb & 3;
        float lsum = 0.f, lcnt = 0.f;
        for (int t = tid; t < TSEQ; t += 256) {
            int token = b * TSEQ + t;
            lsum += tokll[(size_t)slot * MTOK + token];
            lcnt += (y[token] != IGNORE_INDEX) ? 1.f : 0.f;
        }
        rs[tid] = lsum; rc[tid] = lcnt;
        __syncthreads();
        for (int s2 = 128; s2 > 0; s2 >>= 1) {
            if (tid < s2) { rs[tid] += rs[tid + s2]; rc[tid] += rc[tid + s2]; }
            __syncthreads();
        }
        if (tid == 0) seqavg[sb] = rs[0] / rc[0];
        __syncthreads();
    }
    if (tid == 0) {
        float acc = 0.f;
        for (int b = 0; b < BATCH; ++b) {
            float lr   = seqavg[b] - seqavg[BATCH + b];
            float mult = pref[b] ? 1.f : -1.f;
            float z    = BETA * lr * mult;
            float sig  = 1.f / (1.f + expf(-z));
            acc += 1.f - sig;
        }
        out[0] = acc * (1.f / (float)BATCH);
    }
}

// ---------------------------------------------------------------- launcher
extern "C" void kernel_launch(void* const* d_in, const int* in_sizes, int n_in,
                              void* d_out, int out_size, void* d_ws, size_t ws_size,
                              hipStream_t stream) {
    const float* x      = (const float*)d_in[0];
    const float* ref_x  = (const float*)d_in[1];
    const int*   y      = (const int*)d_in[2];
    const int*   pref   = (const int*)d_in[3];
    const float* W      = (const float*)d_in[4];
    const float* ref_W  = (const float*)d_in[5];
    float* out = (float*)d_out;
    char*  ws  = (char*)d_ws;

    const size_t WSZ = (size_t)VOCAB * HDIM * 2;   // 131,072,000 B
    const size_t XSZ = (size_t)MTOK * HDIM * 2;    //   8,388,608 B
    const size_t PSZ = (size_t)2 * MTOK * NCHUNK * 4;  // dual-slot pmax/psum

    // dual-buffer layout needs ~295.3 MB; ws_size is a host constant, so this
    // branch is identical every call (graph-safe).
    const size_t need_dual = 2*WSZ + 2*XSZ + 2*PSZ + (size_t)4*MTOK*4 + 4096;

    if (ws_size >= need_dual) {
        unsigned short* wbf0 = (unsigned short*)(ws);
        unsigned short* wbf1 = (unsigned short*)(ws + WSZ);
        unsigned short* xbf0 = (unsigned short*)(ws + 2*WSZ);
        unsigned short* xbf1 = (unsigned short*)(ws + 2*WSZ + XSZ);
        float* pmax  = (float*)(ws + 2*WSZ + 2*XSZ);
        float* psum  = (float*)(ws + 2*WSZ + 2*XSZ + PSZ);
        float* tlog  = (float*)(ws + 2*WSZ + 2*XSZ + 2*PSZ);
        float* tokll = (float*)(ws + 2*WSZ + 2*XSZ + 2*PSZ + (size_t)2*MTOK*4);

        cvt_all_kernel<<<2*WCVT_BLK + 2*XCVT_BLK, 256, 0, stream>>>(
            W, ref_W, x, ref_x, wbf0, wbf1, xbf0, xbf1);
        gemm_lse_kernel<<<dim3(MTOK/128, VOCAB/128, 2), 256, 0, stream>>>(
            xbf0, xbf1, wbf0, wbf1, y, pmax, psum, tlog, 0);
        finalize_kernel<<<dim3(MTOK/4, 2), 256, 0, stream>>>(
            y, pmax, psum, tlog, tokll, 0);
        tail_kernel<<<1, 256, 0, stream>>>(y, tokll, pref, out);
    } else {
        // serial fallback: single W/X buffer reused per model
        unsigned short* wbf = (unsigned short*)(ws);
        unsigned short* xbf = (unsigned short*)(ws + WSZ);
        float* pmax  = (float*)(ws + WSZ + XSZ);
        float* psum  = (float*)(ws + WSZ + XSZ + PSZ);
        float* tlog  = (float*)(ws + WSZ + XSZ + 2*PSZ);
        float* tokll = (float*)(ws + WSZ + XSZ + 2*PSZ + (size_t)2*MTOK*4);

        for (int model = 0; model < 2; ++model) {
            const float* xin = model ? ref_x : x;
            const float* win = model ? ref_W : W;
            cvt_one_kernel<<<WCVT_BLK, 256, 0, stream>>>(win, wbf);
            cvt_one_kernel<<<XCVT_BLK, 256, 0, stream>>>(xin, xbf);
            gemm_lse_kernel<<<dim3(MTOK/128, VOCAB/128, 1), 256, 0, stream>>>(
                xbf, xbf, wbf, wbf, y, pmax, psum, tlog, model);
            finalize_kernel<<<dim3(MTOK/4, 1), 256, 0, stream>>>(
                y, pmax, psum, tlog, tokll, model);
        }
        tail_kernel<<<1, 256, 0, stream>>>(y, tokll, pref, out);
    }
}

// Round 5
// 1013.336 us; speedup vs baseline: 1.0967x; 1.0967x over previous
//
#include <hip/hip_runtime.h>
#include <math.h>

// Problem constants (B=4, T=512, H=2048, V=32000)
#define BATCH 4
#define TSEQ 512
#define MTOK 2048          // B*T
#define HDIM 2048
#define VOCAB 32000
#define NCHUNK 500         // VOCAB / 64
#define IGNORE_INDEX (-100)
#define BETA 0.1f

// W is quantized as fp8(W*16) and de-scaled in-MFMA via uniform MX scale 2^-4
#define WSCALE 16.0f
#define SCALE_ONE  0x7F7F7F7F   // E8M0 127 = 2^0  in all 4 bytes
#define SCALE_W    0x7B7B7B7B   // E8M0 123 = 2^-4 in all 4 bytes

// convert geometry: 8192 float4s per block (256 thr x 32 iters)
#define CVT_PER_BLOCK 8192
#define WCVT_BLK (VOCAB * HDIM / 4 / CVT_PER_BLOCK)   // 2000 blocks per W
#define XCVT_BLK (MTOK * HDIM / 4 / CVT_PER_BLOCK)    // 128 blocks per x

typedef __attribute__((ext_vector_type(4))) float floatx4;
typedef __attribute__((ext_vector_type(4))) int   intx4;
typedef __attribute__((ext_vector_type(8))) int   intx8;

// ---------------------------------------------------------------- utilities
__device__ __forceinline__ void async_copy16b(const unsigned char* g, unsigned char* l) {
    __builtin_amdgcn_global_load_lds(
        (const __attribute__((address_space(1))) void*)g,
        (__attribute__((address_space(3))) void*)l, 16, 0, 0);
}

// ------------------------------------------------------ fp32 -> fp8 e4m3
// One block converts CVT_PER_BLOCK float4s; each float4 -> 1 packed dword.
// Loads are 16 B/lane wave-contiguous; stores 4 B/lane wave-contiguous.
__device__ __forceinline__ void cvtq_run(const float* __restrict__ src,
                                         unsigned int* __restrict__ dst,
                                         int relblk, float scale) {
    size_t base = (size_t)relblk * CVT_PER_BLOCK + threadIdx.x;
    const floatx4* s4 = (const floatx4*)src;
#pragma unroll
    for (int k = 0; k < 32; ++k) {
        floatx4 a = s4[base + k * 256];
        int lo  = __builtin_amdgcn_cvt_pk_fp8_f32(a[0] * scale, a[1] * scale, 0,  false);
        int all = __builtin_amdgcn_cvt_pk_fp8_f32(a[2] * scale, a[3] * scale, lo, true);
        dst[base + k * 256] = (unsigned int)all;
    }
}

// --------------------------------------------- fp32 -> fp8, all 4 tensors
// grid = 2*WCVT_BLK + 2*XCVT_BLK = 4256 blocks
__global__ __launch_bounds__(256) void cvtq_all_kernel(
        const float* __restrict__ s0, const float* __restrict__ s1,
        const float* __restrict__ s2, const float* __restrict__ s3,
        unsigned int* __restrict__ d0, unsigned int* __restrict__ d1,
        unsigned int* __restrict__ d2, unsigned int* __restrict__ d3) {
    int b = blockIdx.x;
    if (b < WCVT_BLK)                     cvtq_run(s0, d0, b, WSCALE);
    else if (b < 2 * WCVT_BLK)            cvtq_run(s1, d1, b - WCVT_BLK, WSCALE);
    else if (b < 2 * WCVT_BLK + XCVT_BLK) cvtq_run(s2, d2, b - 2 * WCVT_BLK, 1.0f);
    else                                  cvtq_run(s3, d3, b - 2 * WCVT_BLK - XCVT_BLK, 1.0f);
}

// ------------------------------------------------ fp32 -> fp8, one tensor
__global__ __launch_bounds__(256) void cvtq_one_kernel(
        const float* __restrict__ src, unsigned int* __restrict__ dst, float scale) {
    cvtq_run(src, dst, blockIdx.x, scale);
}

// --------------------------------------------------- MX-FP8 GEMM + fused LSE
// C = Xq (M x H fp8) * Wq^T (V x H fp8, pre-scaled x16, MFMA scale 2^-4)
// grid = (M/128, V/128, nmodels), block = 256 (4 waves, each 64x64 via 4x4 of
// 16x16x128 f8f6f4). LDS rows are 128 B = 8 x 16B chunks — identical geometry
// to the verified bf16 version, so the XOR swizzle carries over unchanged:
// global chunk g of row r sits at position g^(r&7); staging permutes the
// SOURCE address (global_load_lds dest must stay wave-uniform base + lane*16).
#define BKF 128
__global__ __launch_bounds__(256, 2) void gemm_lse_fp8_kernel(
        const unsigned char* __restrict__ Xq0,
        const unsigned char* __restrict__ Xq1,
        const unsigned char* __restrict__ Wq0,
        const unsigned char* __restrict__ Wq1,
        const int* __restrict__ y,               // M labels
        float* __restrict__ pmax,                // [slot][M][NCHUNK]
        float* __restrict__ psum,                // [slot][M][NCHUNK]
        float* __restrict__ tlog,                // [slot][M]
        int slot_base)
{
    __shared__ __align__(16) unsigned char sA[128 * BKF];   // 16 KB
    __shared__ __align__(16) unsigned char sB[128 * BKF];   // 16 KB

    const int slot = slot_base + blockIdx.z;
    const unsigned char* __restrict__ Xq = slot ? Xq1 : Xq0;
    const unsigned char* __restrict__ Wq = slot ? Wq1 : Wq0;

    const int tid  = threadIdx.x;
    const int m0   = blockIdx.x * 128;
    const int v0   = blockIdx.y * 128;
    const int w    = tid >> 6;
    const int lane = tid & 63;
    const int wm   = w & 1;         // token half
    const int wn   = w >> 1;        // vocab half
    const int c    = lane & 15;
    const int q    = lane >> 4;

    floatx4 acc[4][4] = {};

    const int e0 = tid * 16;        // byte offset per staging issue

    for (int kt = 0; kt < HDIM / BKF; ++kt) {     // 16 iters
        const int k0 = kt * BKF;
#pragma unroll
        for (int it = 0; it < 4; ++it) {
            int e   = it * 4096 + e0;
            int row = e >> 7;                    // 0..127 (128 B rows)
            int p   = (e >> 4) & 7;              // LDS chunk position
            int col = (p ^ (row & 7)) * 16;      // swizzled global byte col
            async_copy16b(Xq + (size_t)(m0 + row) * HDIM + (k0 + col), &sA[e]);
            async_copy16b(Wq + (size_t)(v0 + row) * HDIM + (k0 + col), &sB[e]);
        }
        __syncthreads();

        // fragments: lane holds k = q*32 .. q*32+31 (chunks 2q, 2q+1)
        intx8 af[4], bf[4];
#pragma unroll
        for (int i = 0; i < 4; ++i) {
            int row = wm * 64 + i * 16 + c;
            int ch0 = (2 * q)     ^ (row & 7);
            int ch1 = (2 * q + 1) ^ (row & 7);
            intx4 lo = *(const intx4*)&sA[row * BKF + ch0 * 16];
            intx4 hi = *(const intx4*)&sA[row * BKF + ch1 * 16];
            intx8 v;
            v[0] = lo[0]; v[1] = lo[1]; v[2] = lo[2]; v[3] = lo[3];
            v[4] = hi[0]; v[5] = hi[1]; v[6] = hi[2]; v[7] = hi[3];
            af[i] = v;
        }
#pragma unroll
        for (int j = 0; j < 4; ++j) {
            int row = wn * 64 + j * 16 + c;
            int ch0 = (2 * q)     ^ (row & 7);
            int ch1 = (2 * q + 1) ^ (row & 7);
            intx4 lo = *(const intx4*)&sB[row * BKF + ch0 * 16];
            intx4 hi = *(const intx4*)&sB[row * BKF + ch1 * 16];
            intx8 v;
            v[0] = lo[0]; v[1] = lo[1]; v[2] = lo[2]; v[3] = lo[3];
            v[4] = hi[0]; v[5] = hi[1]; v[6] = hi[2]; v[7] = hi[3];
            bf[j] = v;
        }
#pragma unroll
        for (int i = 0; i < 4; ++i)
#pragma unroll
            for (int j = 0; j < 4; ++j)
                acc[i][j] = __builtin_amdgcn_mfma_scale_f32_16x16x128_f8f6f4(
                    af[i], bf[j], acc[i][j],
                    0, 0,                 // cbsz=fp8(e4m3), blgp=fp8(e4m3)
                    0, SCALE_ONE,         // A scale: 1.0 (uniform bytes)
                    0, SCALE_W);          // B scale: 2^-4 (uniform bytes)
        __syncthreads();
    }

    // Epilogue: C/D layout is shape-determined: col = lane&15 (vocab),
    // row = q*4+r (token) — same as the bf16 16x16 family.
    const int chunk = blockIdx.y * 2 + wn;   // 64-vocab chunk id
#pragma unroll
    for (int i = 0; i < 4; ++i) {
        float mx[4], sm[4];
#pragma unroll
        for (int r = 0; r < 4; ++r) {
            float m4 = acc[i][0][r];
            m4 = fmaxf(m4, acc[i][1][r]);
            m4 = fmaxf(m4, acc[i][2][r]);
            m4 = fmaxf(m4, acc[i][3][r]);
            mx[r] = m4;
        }
#pragma unroll
        for (int d = 1; d < 16; d <<= 1)
#pragma unroll
            for (int r = 0; r < 4; ++r)
                mx[r] = fmaxf(mx[r], __shfl_xor(mx[r], d, 64));
#pragma unroll
        for (int r = 0; r < 4; ++r) {
            float s = 0.f;
#pragma unroll
            for (int j = 0; j < 4; ++j) s += expf(acc[i][j][r] - mx[r]);
            sm[r] = s;
        }
#pragma unroll
        for (int d = 1; d < 16; d <<= 1)
#pragma unroll
            for (int r = 0; r < 4; ++r)
                sm[r] += __shfl_xor(sm[r], d, 64);

        const int tokenBase = m0 + wm * 64 + i * 16 + q * 4;
        if (c == 0) {
#pragma unroll
            for (int r = 0; r < 4; ++r) {
                pmax[(size_t)(slot * MTOK + tokenBase + r) * NCHUNK + chunk] = mx[r];
                psum[(size_t)(slot * MTOK + tokenBase + r) * NCHUNK + chunk] = sm[r];
            }
        }
        // target-logit capture — LITERAL j index only (runtime index into acc
        // demotes the accumulator to scratch: R1's 12 GB WRITE_SIZE bug)
#pragma unroll
        for (int r = 0; r < 4; ++r) {
            int lab = y[tokenBase + r];
            int rel = lab - (v0 + wn * 64);
            if (rel >= 0 && rel < 64 && (rel & 15) == c) {
#pragma unroll
                for (int j = 0; j < 4; ++j)
                    if ((rel >> 4) == j)
                        tlog[(size_t)slot * MTOK + tokenBase + r] = acc[i][j][r];
            }
        }
    }
}

// --------------------------------------------- per-token logp (wave/token)
// grid = (MTOK/4, nmodels), block = 256 (4 waves, one token each)
__global__ __launch_bounds__(256) void finalize_kernel(
        const int* __restrict__ y,
        const float* __restrict__ pmax,
        const float* __restrict__ psum,
        const float* __restrict__ tlog,
        float* __restrict__ tokll, int slot_base) {
    const int wv    = threadIdx.x >> 6;
    const int lane  = threadIdx.x & 63;
    const int token = blockIdx.x * 4 + wv;
    const int slot  = slot_base + blockIdx.y;

    const float* pm = &pmax[(size_t)(slot * MTOK + token) * NCHUNK];
    const float* ps = &psum[(size_t)(slot * MTOK + token) * NCHUNK];
    float m = -3.4e38f, s = 0.f;
    for (int c2 = lane; c2 < NCHUNK; c2 += 64) {
        float cm = pm[c2];
        float cs = ps[c2];
        if (cm > m) { s = s * expf(m - cm) + cs; m = cm; }
        else        { s += cs * expf(cm - m); }
    }
#pragma unroll
    for (int d = 1; d < 64; d <<= 1) {
        float om = __shfl_xor(m, d, 64);
        float os = __shfl_xor(s, d, 64);
        if (om > m) { s = s * expf(m - om) + os; m = om; }
        else        { s += os * expf(om - m); }
    }
    if (lane == 0) {
        int lab = y[token];
        float lse = m + logf(s);
        tokll[(size_t)slot * MTOK + token] =
            (lab == IGNORE_INDEX) ? 0.f : (tlog[(size_t)slot * MTOK + token] - lse);
    }
}

// ---------------------------------- fused seq-average + KTO loss, 1 block
__global__ __launch_bounds__(256) void tail_kernel(
        const int* __restrict__ y,
        const float* __restrict__ tokll,
        const int* __restrict__ pref,
        float* __restrict__ out) {
    __shared__ float rs[256];
    __shared__ float rc[256];
    __shared__ float seqavg[8];
    const int tid = threadIdx.x;
    for (int sb = 0; sb < 8; ++sb) {
        const int slot = sb >> 2;
        const int b    = sb & 3;
        float lsum = 0.f, lcnt = 0.f;
        for (int t = tid; t < TSEQ; t += 256) {
            int token = b * TSEQ + t;
            lsum += tokll[(size_t)slot * MTOK + token];
            lcnt += (y[token] != IGNORE_INDEX) ? 1.f : 0.f;
        }
        rs[tid] = lsum; rc[tid] = lcnt;
        __syncthreads();
        for (int s2 = 128; s2 > 0; s2 >>= 1) {
            if (tid < s2) { rs[tid] += rs[tid + s2]; rc[tid] += rc[tid + s2]; }
            __syncthreads();
        }
        if (tid == 0) seqavg[sb] = rs[0] / rc[0];
        __syncthreads();
    }
    if (tid == 0) {
        float acc = 0.f;
        for (int b = 0; b < BATCH; ++b) {
            float lr   = seqavg[b] - seqavg[BATCH + b];
            float mult = pref[b] ? 1.f : -1.f;
            float z    = BETA * lr * mult;
            float sig  = 1.f / (1.f + expf(-z));
            acc += 1.f - sig;
        }
        out[0] = acc * (1.f / (float)BATCH);
    }
}

// ---------------------------------------------------------------- launcher
extern "C" void kernel_launch(void* const* d_in, const int* in_sizes, int n_in,
                              void* d_out, int out_size, void* d_ws, size_t ws_size,
                              hipStream_t stream) {
    const float* x      = (const float*)d_in[0];
    const float* ref_x  = (const float*)d_in[1];
    const int*   y      = (const int*)d_in[2];
    const int*   pref   = (const int*)d_in[3];
    const float* W      = (const float*)d_in[4];
    const float* ref_W  = (const float*)d_in[5];
    float* out = (float*)d_out;
    char*  ws  = (char*)d_ws;

    const size_t WQSZ = (size_t)VOCAB * HDIM;      // 65,536,000 B fp8
    const size_t XQSZ = (size_t)MTOK * HDIM;       //  4,194,304 B fp8
    const size_t PSZ  = (size_t)2 * MTOK * NCHUNK * 4;  // dual-slot pmax/psum

    // dual-buffer layout needs ~156 MB; ws_size is a host constant, so this
    // branch is identical every call (graph-safe).
    const size_t need_dual = 2*WQSZ + 2*XQSZ + 2*PSZ + (size_t)4*MTOK*4 + 4096;

    if (ws_size >= need_dual) {
        unsigned char* wq0 = (unsigned char*)(ws);
        unsigned char* wq1 = (unsigned char*)(ws + WQSZ);
        unsigned char* xq0 = (unsigned char*)(ws + 2*WQSZ);
        unsigned char* xq1 = (unsigned char*)(ws + 2*WQSZ + XQSZ);
        float* pmax  = (float*)(ws + 2*WQSZ + 2*XQSZ);
        float* psum  = (float*)(ws + 2*WQSZ + 2*XQSZ + PSZ);
        float* tlog  = (float*)(ws + 2*WQSZ + 2*XQSZ + 2*PSZ);
        float* tokll = (float*)(ws + 2*WQSZ + 2*XQSZ + 2*PSZ + (size_t)2*MTOK*4);

        cvtq_all_kernel<<<2*WCVT_BLK + 2*XCVT_BLK, 256, 0, stream>>>(
            W, ref_W, x, ref_x,
            (unsigned int*)wq0, (unsigned int*)wq1,
            (unsigned int*)xq0, (unsigned int*)xq1);
        gemm_lse_fp8_kernel<<<dim3(MTOK/128, VOCAB/128, 2), 256, 0, stream>>>(
            xq0, xq1, wq0, wq1, y, pmax, psum, tlog, 0);
        finalize_kernel<<<dim3(MTOK/4, 2), 256, 0, stream>>>(
            y, pmax, psum, tlog, tokll, 0);
        tail_kernel<<<1, 256, 0, stream>>>(y, tokll, pref, out);
    } else {
        // serial fallback: single W/X buffer reused per model
        unsigned char* wq = (unsigned char*)(ws);
        unsigned char* xq = (unsigned char*)(ws + WQSZ);
        float* pmax  = (float*)(ws + WQSZ + XQSZ);
        float* psum  = (float*)(ws + WQSZ + XQSZ + PSZ);
        float* tlog  = (float*)(ws + WQSZ + XQSZ + 2*PSZ);
        float* tokll = (float*)(ws + WQSZ + XQSZ + 2*PSZ + (size_t)2*MTOK*4);

        for (int model = 0; model < 2; ++model) {
            const float* xin = model ? ref_x : x;
            const float* win = model ? ref_W : W;
            cvtq_one_kernel<<<WCVT_BLK, 256, 0, stream>>>(win, (unsigned int*)wq, WSCALE);
            cvtq_one_kernel<<<XCVT_BLK, 256, 0, stream>>>(xin, (unsigned int*)xq, 1.0f);
            gemm_lse_fp8_kernel<<<dim3(MTOK/128, VOCAB/128, 1), 256, 0, stream>>>(
                xq, xq, wq, wq, y, pmax, psum, tlog, model);
            finalize_kernel<<<dim3(MTOK/4, 1), 256, 0, stream>>>(
                y, pmax, psum, tlog, tokll, model);
        }
        tail_kernel<<<1, 256, 0, stream>>>(y, tokll, pref, out);
    }
}